// Round 3
// baseline (868.629 us; speedup 1.0000x reference)
//
#include <hip/hip_runtime.h>
#include <hip/hip_bf16.h>

typedef __bf16 bf16x8 __attribute__((ext_vector_type(8)));
typedef float f32x4 __attribute__((ext_vector_type(4)));

#define G_DIM 128

// ---- helpers ----
__device__ __forceinline__ float bf2f(ushort u) {
  return __uint_as_float(((unsigned int)u) << 16);
}

__device__ __forceinline__ bf16x8 cvt8(float4 f0, float4 f1) {
  bf16x8 v;
  v[0] = (__bf16)f0.x; v[1] = (__bf16)f0.y; v[2] = (__bf16)f0.z; v[3] = (__bf16)f0.w;
  v[4] = (__bf16)f1.x; v[5] = (__bf16)f1.y; v[6] = (__bf16)f1.z; v[7] = (__bf16)f1.w;
  return v;
}

// swizzled ushort index into a row-major [rows][128] bf16 LDS tile.
__device__ __forceinline__ int swz_idx(int row, int kc) {
  return (row * 128 + kc * 8) ^ ((row & 7) << 3);
}

// ---- W fp32 -> bf16 pre-conversion (5 matrices packed into one dst) ----
// layout (elem offsets): Wl@0, Wr@16384, W_ih@32768, W_hh@81920, Wfc@131072, total 147456
__global__ void k_wcvt(const float* __restrict__ Wl, const float* __restrict__ Wr,
                       const float* __restrict__ Wih, const float* __restrict__ Whh,
                       const float* __restrict__ Wfc, __bf16* __restrict__ dst) {
  int i = blockIdx.x * blockDim.x + threadIdx.x;
  if (i >= 147456 / 8) return;
  int e = i * 8;
  const float* src; int off;
  if (e < 16384)       { src = Wl;  off = e; }
  else if (e < 32768)  { src = Wr;  off = e - 16384; }
  else if (e < 81920)  { src = Wih; off = e - 32768; }
  else if (e < 131072) { src = Whh; off = e - 81920; }
  else                 { src = Wfc; off = e - 131072; }
  float4 a = ((const float4*)(src + off))[0];
  float4 b = ((const float4*)(src + off))[1];
  *(bf16x8*)(dst + e) = cvt8(a, b);
}

// ---- segment ranges from sorted batch ----
__global__ void k_seg(const int* __restrict__ batch, int* __restrict__ seg, int n, int g) {
  int i = blockIdx.x * blockDim.x + threadIdx.x;
  if (i >= n) return;
  int b = batch[i];
  int prev = (i == 0) ? -1 : batch[i - 1];
  for (int q = prev + 1; q <= b; ++q) seg[q] = i;
  if (i == n - 1) {
    for (int q = b + 1; q <= g; ++q) seg[q] = n;
  }
}

__global__ void k_zero4(float4* __restrict__ p, int n4) {
  int i = blockIdx.x * blockDim.x + threadIdx.x;
  if (i < n4) p[i] = float4{0.f, 0.f, 0.f, 0.f};
}

__global__ void k_relu4(float4* __restrict__ p, int n4) {
  int i = blockIdx.x * blockDim.x + threadIdx.x;
  if (i < n4) {
    float4 v = p[i];
    v.x = fmaxf(v.x, 0.f); v.y = fmaxf(v.y, 0.f);
    v.z = fmaxf(v.z, 0.f); v.w = fmaxf(v.w, 0.f);
    p[i] = v;
  }
}

// ---- big fused kernel: xl = bf16(x @ Wl.T + bl)  AND  pool += segment partial sums of x ----
// Register-prefetched A tiles; vectorized pool with shfl reduce.
__global__ __launch_bounds__(256, 3) void k_xlgemm(const __bf16* __restrict__ Wbf,
                                                   const float* __restrict__ x,
                                                   const float* __restrict__ bias,
                                                   const int* __restrict__ batch,
                                                   __bf16* __restrict__ xl,
                                                   float* __restrict__ pool,
                                                   int rows, int ntiles) {
  __shared__ __align__(16) ushort sB[128 * 128];
  __shared__ __align__(16) ushort sA[64 * 128];
  __shared__ int sBatch[64];
  const int tid = threadIdx.x;
  const int lane = tid & 63;
  const int wv = tid >> 6;
  const int l15 = lane & 15;
  const int kg = lane >> 4;

  // stage W (bf16, already converted) once per block
  for (int c = tid; c < 128 * 16; c += 256) {
    int row = c >> 4, kc = c & 15;
    *(bf16x8*)(&sB[swz_idx(row, kc)]) = *(const bf16x8*)(Wbf + (long)row * 128 + kc * 8);
  }

  float4 pf[8];
  int breg = -1;

  auto issue = [&](long row0) {
    #pragma unroll
    for (int q = 0; q < 4; ++q) {
      int c = tid + q * 256;
      int r = c >> 4, kc = c & 15;
      long gr = row0 + r;
      if (gr < rows) {
        const float4* src = (const float4*)(x + gr * 128 + kc * 8);
        pf[2 * q] = src[0];
        pf[2 * q + 1] = src[1];
      } else {
        pf[2 * q] = float4{0.f, 0.f, 0.f, 0.f};
        pf[2 * q + 1] = float4{0.f, 0.f, 0.f, 0.f};
      }
    }
    if (tid < 64) {
      long gr = row0 + tid;
      breg = (gr < rows) ? batch[gr] : -1;
    }
  };

  issue((long)blockIdx.x * 64);

  for (int tile = blockIdx.x; tile < ntiles; tile += gridDim.x) {
    const long row0 = (long)tile * 64;
    // commit prefetched tile -> LDS
    #pragma unroll
    for (int q = 0; q < 4; ++q) {
      int c = tid + q * 256;
      int r = c >> 4, kc = c & 15;
      *(bf16x8*)(&sA[swz_idx(r, kc)]) = cvt8(pf[2 * q], pf[2 * q + 1]);
    }
    if (tid < 64) sBatch[tid] = breg;
    __syncthreads();

    // issue next tile's loads (overlap with MFMA/epilogue/pool)
    int next = tile + gridDim.x;
    if (next < ntiles) issue((long)next * 64);

    // MFMA: 64x128 tile
    f32x4 acc[8];
    #pragma unroll
    for (int nt = 0; nt < 8; ++nt) acc[nt] = f32x4{0.f, 0.f, 0.f, 0.f};
    const int mrow = wv * 16 + l15;
    #pragma unroll
    for (int ks = 0; ks < 4; ++ks) {
      bf16x8 af = *(const bf16x8*)(&sA[swz_idx(mrow, ks * 4 + kg)]);
      #pragma unroll
      for (int nt = 0; nt < 8; ++nt) {
        bf16x8 bfr = *(const bf16x8*)(&sB[swz_idx(nt * 16 + l15, ks * 4 + kg)]);
        acc[nt] = __builtin_amdgcn_mfma_f32_16x16x32_bf16(af, bfr, acc[nt], 0, 0, 0);
      }
    }
    // epilogue first (frees acc registers before pool)
    #pragma unroll
    for (int nt = 0; nt < 8; ++nt) {
      int col = nt * 16 + l15;
      float bv = bias[col];
      #pragma unroll
      for (int j = 0; j < 4; ++j) {
        long r = row0 + wv * 16 + kg * 4 + j;
        if (r < rows) xl[r * 128 + col] = (__bf16)(acc[nt][j] + bv);
      }
    }

    // pool: wave wv covers rows [wv*16, wv*16+16); lane reads b128 chunks
    {
      int rbase = wv * 16;
      int bfirst = sBatch[rbase], blast = sBatch[rbase + 15];
      if (bfirst == blast) {
        if (bfirst >= 0) {  // fast path: whole slice one segment
          float s8[8];
          #pragma unroll
          for (int q = 0; q < 8; ++q) s8[q] = 0.f;
          #pragma unroll
          for (int j = 0; j < 4; ++j) {
            int row = rbase + kg + j * 4;
            bf16x8 v = *(const bf16x8*)(&sA[swz_idx(row, l15)]);
            #pragma unroll
            for (int q = 0; q < 8; ++q) s8[q] += (float)v[q];
          }
          #pragma unroll
          for (int q = 0; q < 8; ++q) {
            s8[q] += __shfl_xor(s8[q], 16, 64);
            s8[q] += __shfl_xor(s8[q], 32, 64);
          }
          if (kg == 0) {
            float* dst = pool + (long)bfirst * 128 + l15 * 8;
            #pragma unroll
            for (int q = 0; q < 8; ++q) atomicAdd(dst + q, s8[q]);
          }
        }
      } else {  // slow path: segment boundary inside slice
        float s8[8];
        #pragma unroll
        for (int q = 0; q < 8; ++q) s8[q] = 0.f;
        int cb = -1;
        #pragma unroll
        for (int j = 0; j < 4; ++j) {
          int row = rbase + kg + j * 4;
          int b = sBatch[row];
          if (b != cb) {
            if (cb >= 0) {
              float* dst = pool + (long)cb * 128 + l15 * 8;
              #pragma unroll
              for (int q = 0; q < 8; ++q) atomicAdd(dst + q, s8[q]);
            }
            #pragma unroll
            for (int q = 0; q < 8; ++q) s8[q] = 0.f;
            cb = b;
          }
          if (b >= 0) {
            bf16x8 v = *(const bf16x8*)(&sA[swz_idx(row, l15)]);
            #pragma unroll
            for (int q = 0; q < 8; ++q) s8[q] += (float)v[q];
          }
        }
        if (cb >= 0) {
          float* dst = pool + (long)cb * 128 + l15 * 8;
          #pragma unroll
          for (int q = 0; q < 8; ++q) atomicAdd(dst + q, s8[q]);
        }
      }
    }
    __syncthreads();
  }
}

// ---- small GEMM: out[r, c] = bias[c] + sum_k A[r,k] * W[c,k], W pre-converted bf16 ----
__global__ __launch_bounds__(256) void k_gemm128(const float* __restrict__ A,
                                                 const __bf16* __restrict__ W,
                                                 const float* __restrict__ bias,
                                                 float* __restrict__ out,
                                                 int rows) {
  __shared__ __align__(16) ushort sB[128 * 128];
  __shared__ __align__(16) ushort sA[64 * 128];
  const int tid = threadIdx.x;
  const long row0 = (long)blockIdx.x * 64;
  for (int c = tid; c < 128 * 16; c += 256) {
    int row = c >> 4, kc = c & 15;
    *(bf16x8*)(&sB[swz_idx(row, kc)]) = *(const bf16x8*)(W + (long)row * 128 + kc * 8);
  }
  for (int c = tid; c < 64 * 16; c += 256) {
    int r = c >> 4, kc = c & 15;
    long gr = row0 + r;
    bf16x8 v;
    if (gr < rows) {
      const float4* src = (const float4*)(A + gr * 128 + kc * 8);
      v = cvt8(src[0], src[1]);
    } else {
      #pragma unroll
      for (int q = 0; q < 8; ++q) v[q] = (__bf16)0.f;
    }
    *(bf16x8*)(&sA[swz_idx(r, kc)]) = v;
  }
  const int lane = tid & 63;
  const int wv = tid >> 6;
  const int l15 = lane & 15;
  const int kg = lane >> 4;
  __syncthreads();

  f32x4 acc[8];
  #pragma unroll
  for (int nt = 0; nt < 8; ++nt) acc[nt] = f32x4{0.f, 0.f, 0.f, 0.f};
  const int mrow = wv * 16 + l15;
  #pragma unroll
  for (int ks = 0; ks < 4; ++ks) {
    bf16x8 af = *(const bf16x8*)(&sA[swz_idx(mrow, ks * 4 + kg)]);
    #pragma unroll
    for (int nt = 0; nt < 8; ++nt) {
      bf16x8 bfr = *(const bf16x8*)(&sB[swz_idx(nt * 16 + l15, ks * 4 + kg)]);
      acc[nt] = __builtin_amdgcn_mfma_f32_16x16x32_bf16(af, bfr, acc[nt], 0, 0, 0);
    }
  }
  #pragma unroll
  for (int nt = 0; nt < 8; ++nt) {
    int col = nt * 16 + l15;
    float bv = bias[col];
    #pragma unroll
    for (int j = 0; j < 4; ++j) {
      long r = row0 + wv * 16 + kg * 4 + j;
      if (r < rows) out[r * 128 + col] = acc[nt][j] + bv;
    }
  }
}

// ---- fused GATv2: 4 rows per iteration, 16-lane groups, online softmax ----
__global__ __launch_bounds__(256) void k_gat(const __bf16* __restrict__ xl,
                                             const float* __restrict__ xr,
                                             const int* __restrict__ seg,
                                             const float* __restrict__ att,
                                             const float* __restrict__ gat_bias,
                                             float* __restrict__ h, int G) {
  int wid = (blockIdx.x << 2) + (threadIdx.x >> 6);
  if (wid >= G) return;
  int lane = threadIdx.x & 63;
  int grp = lane >> 4, li = lane & 15;
  int s = seg[wid], e = seg[wid + 1];
  int d0 = li * 8;

  const float* xrp = xr + (long)wid * G_DIM + d0;
  float xrv[8], atv[8];
  {
    float4 a0 = *(const float4*)(xrp);
    float4 a1 = *(const float4*)(xrp + 4);
    float4 t0 = *(const float4*)(att + d0);
    float4 t1 = *(const float4*)(att + d0 + 4);
    xrv[0]=a0.x; xrv[1]=a0.y; xrv[2]=a0.z; xrv[3]=a0.w;
    xrv[4]=a1.x; xrv[5]=a1.y; xrv[6]=a1.z; xrv[7]=a1.w;
    atv[0]=t0.x; atv[1]=t0.y; atv[2]=t0.z; atv[3]=t0.w;
    atv[4]=t1.x; atv[5]=t1.y; atv[6]=t1.z; atv[7]=t1.w;
  }

  float m = -1e30f, den = 0.f;
  float acc[8];
  #pragma unroll
  for (int q = 0; q < 8; ++q) acc[q] = 0.f;

  for (int base = s; base < e; base += 4) {
    int i = base + grp;
    bool valid = i < e;
    float xv[8];
    if (valid) {
      bf16x8 v = *(const bf16x8*)((const ushort*)xl + (long)i * G_DIM + d0);
      #pragma unroll
      for (int q = 0; q < 8; ++q) xv[q] = (float)v[q];
    } else {
      #pragma unroll
      for (int q = 0; q < 8; ++q) xv[q] = 0.f;
    }
    float p = 0.f;
    #pragma unroll
    for (int q = 0; q < 8; ++q) {
      float t = xv[q] + xrv[q];
      t = fmaxf(t, 0.f) + 0.01f * fminf(t, 0.f);
      p = fmaf(t, atv[q], p);
    }
    p += __shfl_xor(p, 1, 64);
    p += __shfl_xor(p, 2, 64);
    p += __shfl_xor(p, 4, 64);
    p += __shfl_xor(p, 8, 64);
    float pe = valid ? p : -1e30f;
    float e1 = __shfl_xor(pe, 16, 64);
    float e2 = __shfl_xor(pe, 32, 64);
    float e3 = __shfl_xor(e1, 32, 64);
    float nm = fmaxf(m, fmaxf(fmaxf(pe, e1), fmaxf(e2, e3)));
    float sc = __expf(m - nm);
    float w0 = __expf(pe - nm);
    den = den * sc + w0 + __expf(e1 - nm) + __expf(e2 - nm) + __expf(e3 - nm);
    #pragma unroll
    for (int q = 0; q < 8; ++q) acc[q] = acc[q] * sc + w0 * xv[q];
    m = nm;
  }
  #pragma unroll
  for (int q = 0; q < 8; ++q) {
    acc[q] += __shfl_xor(acc[q], 16, 64);
    acc[q] += __shfl_xor(acc[q], 32, 64);
  }
  if (grp == 0) {
    float inv = (e > s) ? 1.f / den : 0.f;
    float o[8];
    #pragma unroll
    for (int q = 0; q < 8; ++q) {
      float v = acc[q] * inv + gat_bias[d0 + q];
      o[q] = v > 0.f ? v : __expf(v) - 1.f;  // elu
    }
    float* dst = h + (long)wid * G_DIM + d0;
    *(float4*)(dst) = float4{o[0], o[1], o[2], o[3]};
    *(float4*)(dst + 4) = float4{o[4], o[5], o[6], o[7]};
  }
}

// ---- fused GRU: gi=h@W_ih.T, gh=cur@W_hh.T (bf16 W), gate math, relu -> nxt ----
__global__ __launch_bounds__(256) void k_grublock(const float* __restrict__ h,
                                                  const float* __restrict__ cur,
                                                  const __bf16* __restrict__ W_ih,
                                                  const __bf16* __restrict__ W_hh,
                                                  const float* __restrict__ b_ih,
                                                  const float* __restrict__ b_hh,
                                                  float* __restrict__ nxt, int G) {
  __shared__ __align__(16) ushort sA1[64 * 128];  // h tile
  __shared__ __align__(16) ushort sA2[64 * 128];  // cur tile
  __shared__ __align__(16) ushort sW[128 * 128];  // one gate of one W at a time
  const int tid = threadIdx.x;
  const int lane = tid & 63, wv = tid >> 6, l15 = lane & 15, kg = lane >> 4;
  const long row0 = (long)blockIdx.x * 64;
  const int mrow = wv * 16 + l15;

  for (int c = tid; c < 64 * 16; c += 256) {
    int r = c >> 4, kc = c & 15;
    long gr = row0 + r;
    const float4* s1 = (const float4*)(h + gr * 128 + kc * 8);
    const float4* s2 = (const float4*)(cur + gr * 128 + kc * 8);
    *(bf16x8*)(&sA1[swz_idx(r, kc)]) = cvt8(s1[0], s1[1]);
    *(bf16x8*)(&sA2[swz_idx(r, kc)]) = cvt8(s2[0], s2[1]);
  }

  f32x4 rp[8], zp[8], inn[8], hnn[8];
  #pragma unroll
  for (int nt = 0; nt < 8; ++nt) {
    rp[nt] = f32x4{0.f, 0.f, 0.f, 0.f};
    zp[nt] = f32x4{0.f, 0.f, 0.f, 0.f};
    inn[nt] = f32x4{0.f, 0.f, 0.f, 0.f};
    hnn[nt] = f32x4{0.f, 0.f, 0.f, 0.f};
  }

#define STAGE_W(WSRC, gate)                                                   \
  __syncthreads();                                                            \
  for (int c = tid; c < 128 * 16; c += 256) {                                 \
    int r = c >> 4, kc = c & 15;                                              \
    *(bf16x8*)(&sW[swz_idx(r, kc)]) =                                         \
        *(const bf16x8*)((WSRC) + ((long)(gate)*128 + r) * 128 + kc * 8);     \
  }                                                                           \
  __syncthreads();

#define MM(ACC, SAX)                                                          \
  _Pragma("unroll") for (int ks = 0; ks < 4; ++ks) {                          \
    bf16x8 af = *(const bf16x8*)(&SAX[swz_idx(mrow, ks * 4 + kg)]);           \
    _Pragma("unroll") for (int nt = 0; nt < 8; ++nt) {                        \
      bf16x8 bfr = *(const bf16x8*)(&sW[swz_idx(nt * 16 + l15, ks * 4 + kg)]);\
      ACC[nt] = __builtin_amdgcn_mfma_f32_16x16x32_bf16(af, bfr, ACC[nt], 0, 0, 0); \
    }                                                                         \
  }

  STAGE_W(W_ih, 0) MM(rp, sA1)
  STAGE_W(W_hh, 0) MM(rp, sA2)
  STAGE_W(W_ih, 1) MM(zp, sA1)
  STAGE_W(W_hh, 1) MM(zp, sA2)
  STAGE_W(W_ih, 2) MM(inn, sA1)
  STAGE_W(W_hh, 2) MM(hnn, sA2)
#undef STAGE_W
#undef MM

  #pragma unroll
  for (int nt = 0; nt < 8; ++nt) {
    int col = nt * 16 + l15;
    float bir = b_ih[col], biz = b_ih[col + 128], bin = b_ih[col + 256];
    float bhr = b_hh[col], bhz = b_hh[col + 128], bhn = b_hh[col + 256];
    #pragma unroll
    for (int j = 0; j < 4; ++j) {
      long r = row0 + wv * 16 + kg * 4 + j;
      if (r >= G) continue;
      float pre_r = rp[nt][j] + bir + bhr;
      float pre_z = zp[nt][j] + biz + bhz;
      float rr = 1.f / (1.f + __expf(-pre_r));
      float zz = 1.f / (1.f + __expf(-pre_z));
      float nn = tanhf(inn[nt][j] + bin + rr * (hnn[nt][j] + bhn));
      float hp = cur[r * 128 + col];
      nxt[r * 128 + col] = fmaxf((1.f - zz) * nn + zz * hp, 0.f);
    }
  }
}

extern "C" void kernel_launch(void* const* d_in, const int* in_sizes, int n_in,
                              void* d_out, int out_size, void* d_ws, size_t ws_size,
                              hipStream_t stream) {
  const float* x        = (const float*)d_in[0];
  const int*   batch    = (const int*)d_in[1];
  const float* Wl       = (const float*)d_in[2];
  const float* bl       = (const float*)d_in[3];
  const float* Wr       = (const float*)d_in[4];
  const float* br       = (const float*)d_in[5];
  const float* att      = (const float*)d_in[6];
  const float* gat_bias = (const float*)d_in[7];
  const float* W_ih     = (const float*)d_in[8];
  const float* W_hh     = (const float*)d_in[9];
  const float* b_ih     = (const float*)d_in[10];
  const float* b_hh     = (const float*)d_in[11];
  const float* Wfc      = (const float*)d_in[12];
  const float* bfc      = (const float*)d_in[13];
  const int N = in_sizes[1];
  const int G = out_size / G_DIM;
  float* outf = (float*)d_out;

  char* ws = (char*)d_ws;
  size_t off = 0;
  auto alloc = [&](size_t bytes) -> void* {
    void* p = ws + off;
    off = (off + bytes + 255) & ~(size_t)255;
    return p;
  };
  int*    seg   = (int*)alloc(((size_t)G + 1) * sizeof(int));
  float*  out_a = (float*)alloc((size_t)G * G_DIM * sizeof(float));
  float*  out_b = (float*)alloc((size_t)G * G_DIM * sizeof(float));
  float*  xr    = (float*)alloc((size_t)G * G_DIM * sizeof(float));
  float*  hbuf  = (float*)alloc((size_t)G * G_DIM * sizeof(float));
  __bf16* wsW   = (__bf16*)alloc((size_t)147456 * sizeof(ushort));
  __bf16* xl    = (__bf16*)alloc((size_t)N * G_DIM * sizeof(ushort));
  (void)ws_size; (void)n_in;

  __bf16* Wlb  = wsW;
  __bf16* Wrb  = wsW + 16384;
  __bf16* Wihb = wsW + 32768;
  __bf16* Whhb = wsW + 81920;
  __bf16* Wfcb = wsW + 131072;

  const int pool4 = G * G_DIM / 4;

  k_wcvt<<<(147456 / 8 + 255) / 256, 256, 0, stream>>>(Wl, Wr, W_ih, W_hh, Wfc, wsW);
  k_seg<<<(N + 255) / 256, 256, 0, stream>>>(batch, seg, N, G);
  k_zero4<<<(pool4 + 255) / 256, 256, 0, stream>>>((float4*)out_a, pool4);

  const int ntiles_big = (N + 63) / 64;
  k_xlgemm<<<768, 256, 0, stream>>>(Wlb, x, bl, batch, xl, out_a, N, ntiles_big);
  k_relu4<<<(pool4 + 255) / 256, 256, 0, stream>>>((float4*)out_a, pool4);

  const int ntiles_g = (G + 63) / 64;
  const float* cur = out_a;
  float* nxt = out_b;
  for (int t = 0; t < 3; ++t) {
    k_gemm128<<<ntiles_g, 256, 0, stream>>>(cur, Wrb, br, xr, G);
    k_gat<<<(G + 3) / 4, 256, 0, stream>>>(xl, xr, seg, att, gat_bias, hbuf, G);
    k_grublock<<<ntiles_g, 256, 0, stream>>>(hbuf, cur, Wihb, Whhb, b_ih, b_hh, nxt, G);
    const float* tmp = cur;
    cur = nxt;
    nxt = (float*)tmp;
  }
  k_gemm128<<<ntiles_g, 256, 0, stream>>>(cur, Wfcb, bfc, outf, G);
}